// Round 6
// baseline (1863.788 us; speedup 1.0000x reference)
//
#include <hip/hip_runtime.h>
#include <math.h>

#define NN 100000      // nodes
#define NE 3200000     // edges
#define NIN 128
#define HH 64
#define NB 2048        // graphs
#define RO 1024

typedef unsigned short u16;
typedef __attribute__((ext_vector_type(8))) short short8;
typedef __attribute__((ext_vector_type(4))) float f32x4;

__device__ __forceinline__ float sigmoidf_(float x){ return 1.f/(1.f+expf(-x)); }
__device__ __forceinline__ float dot4_(float4 a, float4 b){ return a.x*b.x + a.y*b.y + a.z*b.z + a.w*b.w; }
__device__ __forceinline__ u16 f2bf(float f){
  unsigned u = __float_as_uint(f);
  return (u16)((u + 0x7FFFu + ((u>>16)&1u)) >> 16);
}
__device__ __forceinline__ float bf2f(u16 v){
  return __uint_as_float(((unsigned)v) << 16);
}

// ---------------- CSR build ----------------
__global__ void k_cnt(const int* __restrict__ dst, const int* __restrict__ batch,
                      int* __restrict__ cnt, int* __restrict__ gcnt){
  int tid = blockIdx.x*256 + threadIdx.x;
  int stride = gridDim.x*256;
  for (int g = tid; g < NE/4; g += stride){
    int4 d4 = ((const int4*)dst)[g];
    atomicAdd(&cnt[d4.x], 1); atomicAdd(&cnt[d4.y], 1);
    atomicAdd(&cnt[d4.z], 1); atomicAdd(&cnt[d4.w], 1);
  }
  for (int g = tid; g < NN/4; g += stride){
    int4 b4 = ((const int4*)batch)[g];
    atomicAdd(&gcnt[b4.x], 1); atomicAdd(&gcnt[b4.y], 1);
    atomicAdd(&gcnt[b4.z], 1); atomicAdd(&gcnt[b4.w], 1);
  }
}
// two single-block exclusive scans (block 0: nodes, block 1: graphs)
// also seeds fill2[i] = exclusive prefix (so k_fill needs no rowptr read)
__device__ void scan_body(const int* in, int* out, int* fill2, int n){
  __shared__ int sums[1024];
  int tid = threadIdx.x;
  int chunk = (n + 1023) >> 10;
  int beg = tid * chunk; if (beg > n) beg = n;
  int end = beg + chunk; if (end > n) end = n;
  int s = 0;
  for (int i = beg; i < end; ++i) s += in[i];
  sums[tid] = s; __syncthreads();
  for (int off = 1; off < 1024; off <<= 1){
    int v = (tid >= off) ? sums[tid-off] : 0;
    __syncthreads();
    sums[tid] += v;
    __syncthreads();
  }
  int base = (tid==0) ? 0 : sums[tid-1];
  for (int i = beg; i < end; ++i){
    out[i] = base;
    if (fill2 != nullptr) fill2[i] = base;
    base += in[i];
  }
  if (tid == 1023) out[n] = base;
}
__global__ void k_scan2(const int* __restrict__ in0, int* __restrict__ out0, int* __restrict__ fill0, int n0,
                        const int* __restrict__ in1, int* __restrict__ out1, int n1){
  if (blockIdx.x == 0) scan_body(in0, out0, fill0, n0);
  else scan_body(in1, out1, nullptr, n1);
}
// fill[] pre-seeded with rowptr: atomicAdd gives the absolute col slot directly
__global__ void k_fill(const int* __restrict__ src, const int* __restrict__ dst,
                       int* __restrict__ fill, int* __restrict__ col){
  int tid = blockIdx.x*256 + threadIdx.x;
  int stride = gridDim.x*256;
  for (int g = tid; g < NE/4; g += stride){
    int4 d4 = ((const int4*)dst)[g];
    int4 s4 = ((const int4*)src)[g];
    int p0 = atomicAdd(&fill[d4.x], 1);
    int p1 = atomicAdd(&fill[d4.y], 1);
    int p2 = atomicAdd(&fill[d4.z], 1);
    int p3 = atomicAdd(&fill[d4.w], 1);
    col[p0] = s4.x; col[p1] = s4.y; col[p2] = s4.z; col[p3] = s4.w;
  }
}

// ---------------- weight prep: bf16 + fragment pre-swizzle (MFMA kernels only) ----------------
__global__ void k_prep(
    const float* __restrict__ Wp, const float* __restrict__ Wl, const float* __restrict__ Wr,
    const float* __restrict__ sWih, const float* __restrict__ sWhh,
    const float* __restrict__ rWih, const float* __restrict__ rWhh,
    u16* __restrict__ pB_proj, u16* __restrict__ pB_sage,
    u16* __restrict__ pB_gruS, u16* __restrict__ pB_gruR)
{
  int id = blockIdx.x*256 + threadIdx.x;
  if (id >= 8192) return;
  const float* sp; u16* d;
  if (id < 1024){
    int fi = id; d = pB_proj + (size_t)fi*8;
    int lane = fi&63, kt=(fi>>6)&3, ct=fi>>8;
    int rr = ct*16 + (lane&15), k0 = kt*32 + (lane>>4)*8;
    sp = &Wp[(size_t)rr*NIN + k0];
  } else if (id < 2048){
    int fi = id - 1024; d = pB_sage + (size_t)fi*8;
    int lane = fi&63, kt=(fi>>6)&3, ct=fi>>8;
    int rr = ct*16 + (lane&15), k0 = kt*32 + (lane>>4)*8;
    sp = (k0 < 64) ? &Wl[(size_t)rr*HH + k0] : &Wr[(size_t)rr*HH + (k0-64)];
  } else {
    int base = id - 2048;
    const float* Wih; const float* Whh; u16* pb; int fi;
    if (base < 3072){ pb = pB_gruS; Wih = sWih; Whh = sWhh; fi = base; }
    else            { pb = pB_gruR; Wih = rWih; Whh = rWhh; fi = base - 3072; }
    int lane = fi&63, kt=(fi>>6)&1, c2=fi>>7;
    const float* W2 = (c2 < 12) ? Wih : Whh;
    int ct = (c2 < 12) ? c2 : c2 - 12;
    int rr = ct*16 + (lane&15), k0 = kt*32 + (lane>>4)*8;
    sp = &W2[(size_t)rr*HH + k0];
    d = pb + (size_t)fi*8;
  }
  #pragma unroll
  for (int q = 0; q < 8; ++q) d[q] = f2bf(sp[q]);
}

// ---------------- proj = relu(x@W_p^T + b) via MFMA; init proj, hs, hr, hsb ----------------
__global__ __launch_bounds__(256) void k_proj(
    const float* __restrict__ x, const u16* __restrict__ pB, const float* __restrict__ bp,
    float* __restrict__ proj, float* __restrict__ hs, float* __restrict__ hr,
    u16* __restrict__ hsb)
{
  __shared__ u16 s_a[64][136];
  __shared__ u16 s_b[4*4*64*8];
  __shared__ float s_bias[64];
  const int t = threadIdx.x;
  const int n0 = blockIdx.x * 64;
  for (int idx = t; idx < 1024; idx += 256)
    ((short8*)s_b)[idx] = ((const short8*)pB)[idx];
  if (t < 64) s_bias[t] = bp[t];
  {
    int r = t>>2, cg = t&3, node = n0 + r;
    u16* d = &s_a[r][cg*32];
    if (node < NN){
      const float4* xp = (const float4*)&x[(size_t)node*NIN + cg*32];
      #pragma unroll
      for (int q = 0; q < 8; ++q){
        float4 v = xp[q];
        d[q*4+0]=f2bf(v.x); d[q*4+1]=f2bf(v.y); d[q*4+2]=f2bf(v.z); d[q*4+3]=f2bf(v.w);
      }
    } else {
      #pragma unroll
      for (int q = 0; q < 32; ++q) d[q] = 0;
    }
  }
  __syncthreads();
  const int lane = t & 63, nt = t >> 6;
  const int colp = lane & 15, rowg = lane >> 4;
  f32x4 acc[4];
  #pragma unroll
  for (int i = 0; i < 4; ++i) acc[i] = (f32x4){0.f,0.f,0.f,0.f};
  #pragma unroll
  for (int kt = 0; kt < 4; ++kt){
    short8 a = *(const short8*)&s_a[nt*16 + colp][kt*32 + rowg*8];
    #pragma unroll
    for (int ct = 0; ct < 4; ++ct){
      short8 b = *(const short8*)&s_b[((ct*4 + kt)*64 + lane)*8];
      acc[ct] = __builtin_amdgcn_mfma_f32_16x16x32_bf16(a, b, acc[ct], 0, 0, 0);
    }
  }
  #pragma unroll
  for (int reg = 0; reg < 4; ++reg){
    int node = n0 + nt*16 + rowg*4 + reg;
    if (node >= NN) continue;
    #pragma unroll
    for (int ct = 0; ct < 4; ++ct){
      int j = ct*16 + colp;
      float v = fmaxf(acc[ct][reg] + s_bias[j], 0.f);
      size_t o = (size_t)node*HH + j;
      proj[o] = v; hs[o] = v; hr[o] = v;
      hsb[o] = f2bf(v);
    }
  }
}

// ---------------- agg[n] = mean over neighbors of hsb (bf16 in, fp32 out) ----------------
__global__ void k_agg(const u16* __restrict__ hb, const int* __restrict__ rowptr,
                      const int* __restrict__ col, float* __restrict__ agg){
  int node = blockIdx.x*4 + (threadIdx.x >> 6);
  int lane = threadIdx.x & 63;
  if (node >= NN) return;
  int beg = rowptr[node], end = rowptr[node+1];
  float s0=0.f, s1=0.f, s2=0.f, s3=0.f;
  int i = beg;
  for (; i < end && (i & 3); ++i) s0 += bf2f(hb[(size_t)col[i]*HH + lane]);
  for (; i + 4 <= end; i += 4){
    int4 c = *(const int4*)&col[i];
    s0 += bf2f(hb[(size_t)c.x*HH + lane]);
    s1 += bf2f(hb[(size_t)c.y*HH + lane]);
    s2 += bf2f(hb[(size_t)c.z*HH + lane]);
    s3 += bf2f(hb[(size_t)c.w*HH + lane]);
  }
  for (; i < end; ++i) s0 += bf2f(hb[(size_t)col[i]*HH + lane]);
  float s = (s0+s1)+(s2+s3);
  float invd = 1.f / fmaxf((float)(end - beg), 1.f);
  agg[(size_t)node*HH + lane] = s * invd;
}

// ---------------- am = relu([agg|hs]@[Wl;Wr]^T + bl) via MFMA, fp32 in-place ----------------
__global__ __launch_bounds__(256) void k_sage(
    const u16* __restrict__ hsb, const u16* __restrict__ pB,
    const float* __restrict__ bl, float* __restrict__ agg)
{
  __shared__ u16 s_a[64][136];
  __shared__ u16 s_b[4*4*64*8];
  __shared__ float s_bias[64];
  const int t = threadIdx.x;
  const int n0 = blockIdx.x * 64;
  for (int idx = t; idx < 1024; idx += 256)
    ((short8*)s_b)[idx] = ((const short8*)pB)[idx];
  if (t < 64) s_bias[t] = bl[t];
  {
    int r = t>>2, cg = t&3, node = n0 + r;
    if (node < NN){
      if (cg < 2){
        u16* d = &s_a[r][cg*32];
        const float4* xp = (const float4*)&agg[(size_t)node*HH + cg*32];
        #pragma unroll
        for (int q = 0; q < 8; ++q){
          float4 v = xp[q];
          d[q*4+0]=f2bf(v.x); d[q*4+1]=f2bf(v.y); d[q*4+2]=f2bf(v.z); d[q*4+3]=f2bf(v.w);
        }
      } else {
        // 32 bf16 = 4 x short8 (R5 bug: only 2 copied -> garbage LDS)
        short8* d8 = (short8*)&s_a[r][cg*32];
        const short8* sp = (const short8*)&hsb[(size_t)node*HH + (cg-2)*32];
        d8[0] = sp[0]; d8[1] = sp[1]; d8[2] = sp[2]; d8[3] = sp[3];
      }
    } else {
      u16* dz = &s_a[r][cg*32];
      #pragma unroll
      for (int q = 0; q < 32; ++q) dz[q] = 0;
    }
  }
  __syncthreads();
  const int lane = t & 63, nt = t >> 6;
  const int colp = lane & 15, rowg = lane >> 4;
  f32x4 acc[4];
  #pragma unroll
  for (int i = 0; i < 4; ++i) acc[i] = (f32x4){0.f,0.f,0.f,0.f};
  #pragma unroll
  for (int kt = 0; kt < 4; ++kt){
    short8 a = *(const short8*)&s_a[nt*16 + colp][kt*32 + rowg*8];
    #pragma unroll
    for (int ct = 0; ct < 4; ++ct){
      short8 b = *(const short8*)&s_b[((ct*4 + kt)*64 + lane)*8];
      acc[ct] = __builtin_amdgcn_mfma_f32_16x16x32_bf16(a, b, acc[ct], 0, 0, 0);
    }
  }
  __syncthreads();   // all reads of agg done before in-place write
  #pragma unroll
  for (int reg = 0; reg < 4; ++reg){
    int node = n0 + nt*16 + rowg*4 + reg;
    if (node >= NN) continue;
    #pragma unroll
    for (int ct = 0; ct < 4; ++ct){
      int j = ct*16 + colp;
      float v = fmaxf(acc[ct][reg] + s_bias[j], 0.f);
      agg[(size_t)node*HH + j] = v;
    }
  }
}

// ---------------- fused gate + GRU cell via MFMA, in-place h update ----------------
__global__ __launch_bounds__(256) void k_gru(
    float* __restrict__ h, const float* __restrict__ am,
    const float* __restrict__ gW, const float* __restrict__ gb,
    const u16* __restrict__ pB,
    const float* __restrict__ bih, const float* __restrict__ bhh,
    float* __restrict__ out_gate, u16* __restrict__ bfout)
{
  __shared__ u16 s_b[2*12*2*64*8];      // 49152 B
  __shared__ u16 s_x[64][72];
  __shared__ u16 s_h[64][72];
  __shared__ float s_bi[192], s_bh[192];
  const int t = threadIdx.x;
  const int n0 = blockIdx.x * 64;
  for (int idx = t; idx < 3072; idx += 256)
    ((short8*)s_b)[idx] = ((const short8*)pB)[idx];
  if (t < 192){ s_bi[t] = bih[t]; s_bh[t] = bhh[t]; }
  const float gb0 = gb[0];
  {
    int r = t>>2, cg = t&3, node = n0 + r;
    u16* dh = &s_h[r][cg*16];
    u16* dx = &s_x[r][cg*16];
    if (node < NN){
      float hv[16];
      const float4* hp = (const float4*)&h[(size_t)node*HH + cg*16];
      #pragma unroll
      for (int q = 0; q < 4; ++q){
        float4 v = hp[q];
        hv[q*4+0]=v.x; hv[q*4+1]=v.y; hv[q*4+2]=v.z; hv[q*4+3]=v.w;
      }
      const float* gwp = &gW[cg*16];
      float p = 0.f;
      #pragma unroll
      for (int q = 0; q < 16; ++q) p += hv[q]*gwp[q];
      p += __shfl_xor(p, 1);
      p += __shfl_xor(p, 2);
      float gate = sigmoidf_(p + gb0);
      if (out_gate != nullptr && cg == 0) out_gate[node] = gate;
      #pragma unroll
      for (int q = 0; q < 16; ++q) dh[q] = f2bf(hv[q]);
      const float4* ap = (const float4*)&am[(size_t)node*HH + cg*16];
      #pragma unroll
      for (int q = 0; q < 4; ++q){
        float4 v = ap[q];
        dx[q*4+0]=f2bf(gate*v.x); dx[q*4+1]=f2bf(gate*v.y);
        dx[q*4+2]=f2bf(gate*v.z); dx[q*4+3]=f2bf(gate*v.w);
      }
    } else {
      #pragma unroll
      for (int q = 0; q < 16; ++q){ dh[q] = 0; dx[q] = 0; }
    }
  }
  __syncthreads();
  const int lane = t & 63, nt = t >> 6;
  const int colp = lane & 15, rowg = lane >> 4;
  f32x4 acc[24];
  #pragma unroll
  for (int i = 0; i < 24; ++i) acc[i] = (f32x4){0.f,0.f,0.f,0.f};
  const int arow = nt*16 + colp;
  #pragma unroll
  for (int kt = 0; kt < 2; ++kt){
    short8 ax = *(const short8*)&s_x[arow][kt*32 + rowg*8];
    short8 ah = *(const short8*)&s_h[arow][kt*32 + rowg*8];
    #pragma unroll
    for (int ct = 0; ct < 12; ++ct){
      short8 b0 = *(const short8*)&s_b[((ct*2 + kt)*64 + lane)*8];
      acc[ct] = __builtin_amdgcn_mfma_f32_16x16x32_bf16(ax, b0, acc[ct], 0, 0, 0);
      short8 b1 = *(const short8*)&s_b[(((12 + ct)*2 + kt)*64 + lane)*8];
      acc[12+ct] = __builtin_amdgcn_mfma_f32_16x16x32_bf16(ah, b1, acc[12+ct], 0, 0, 0);
    }
  }
  #pragma unroll
  for (int reg = 0; reg < 4; ++reg){
    int node = n0 + nt*16 + rowg*4 + reg;
    if (node >= NN) continue;
    #pragma unroll
    for (int jt = 0; jt < 4; ++jt){
      int j = jt*16 + colp;
      float ir = acc[jt][reg]      + s_bi[j];
      float iz = acc[4+jt][reg]    + s_bi[64+j];
      float in_ = acc[8+jt][reg]   + s_bi[128+j];
      float hr_ = acc[12+jt][reg]  + s_bh[j];
      float hz = acc[16+jt][reg]   + s_bh[64+j];
      float hn = acc[20+jt][reg]   + s_bh[128+j];
      float rg = sigmoidf_(ir + hr_);
      float zg = sigmoidf_(iz + hz);
      float ng = tanhf(in_ + rg*hn);
      size_t o = (size_t)node*HH + j;
      float ho = h[o];
      float hv = (1.f - zg)*ng + zg*ho;
      h[o] = hv;
      if (bfout != nullptr) bfout[o] = f2bf(hv);
    }
  }
}

// ---------------- LSTM cell, 8 graphs per block (fp32 weights) ----------------
__global__ __launch_bounds__(256) void k_lstm(
    const float* __restrict__ q_star, const float* __restrict__ hin, const float* __restrict__ cin,
    const float* __restrict__ Wih, const float* __restrict__ Whh,
    const float* __restrict__ bih, const float* __restrict__ bhh,
    float* __restrict__ hout, float* __restrict__ cout)
{
  __shared__ float s_q[8][384];
  __shared__ float s_h[8][192];
  __shared__ float s_g[8][768];
  const int t = threadIdx.x;
  const int b0 = blockIdx.x * 8;
  for (int i = t; i < 8*384; i += 256){ int g=i/384, k=i%384; s_q[g][k] = q_star[(size_t)(b0+g)*384 + k]; }
  for (int i = t; i < 8*192; i += 256){ int g=i/192, k=i%192; s_h[g][k] = hin[(size_t)(b0+g)*192 + k]; }
  __syncthreads();
  float acc[3][8];
  #pragma unroll
  for (int m = 0; m < 3; ++m){
    float bb = bih[t+256*m] + bhh[t+256*m];
    #pragma unroll
    for (int g = 0; g < 8; ++g) acc[m][g] = bb;
  }
  for (int k4 = 0; k4 < 96; ++k4){
    float4 w0 = *(const float4*)&Wih[(size_t)(t)*384     + k4*4];
    float4 w1 = *(const float4*)&Wih[(size_t)(t+256)*384 + k4*4];
    float4 w2 = *(const float4*)&Wih[(size_t)(t+512)*384 + k4*4];
    #pragma unroll
    for (int g = 0; g < 8; ++g){
      float4 q = *(const float4*)&s_q[g][k4*4];
      acc[0][g] += dot4_(w0,q); acc[1][g] += dot4_(w1,q); acc[2][g] += dot4_(w2,q);
    }
  }
  for (int k4 = 0; k4 < 48; ++k4){
    float4 w0 = *(const float4*)&Whh[(size_t)(t)*192     + k4*4];
    float4 w1 = *(const float4*)&Whh[(size_t)(t+256)*192 + k4*4];
    float4 w2 = *(const float4*)&Whh[(size_t)(t+512)*192 + k4*4];
    #pragma unroll
    for (int g = 0; g < 8; ++g){
      float4 hq = *(const float4*)&s_h[g][k4*4];
      acc[0][g] += dot4_(w0,hq); acc[1][g] += dot4_(w1,hq); acc[2][g] += dot4_(w2,hq);
    }
  }
  #pragma unroll
  for (int m = 0; m < 3; ++m){
    int j = t + 256*m;
    #pragma unroll
    for (int g = 0; g < 8; ++g) s_g[g][j] = acc[m][g];
  }
  __syncthreads();
  for (int task = t; task < 8*192; task += 256){
    int g = task / 192, d = task % 192;
    float i_ = s_g[g][d], f_ = s_g[g][192+d], gg = s_g[g][384+d], o_ = s_g[g][576+d];
    float c = sigmoidf_(f_)*cin[(size_t)(b0+g)*192 + d] + sigmoidf_(i_)*tanhf(gg);
    float hn = sigmoidf_(o_)*tanhf(c);
    cout[(size_t)(b0+g)*192 + d] = c;
    hout[(size_t)(b0+g)*192 + d] = hn;
  }
}

// ---------------- fused e-dot + segment softmax + weighted sum (fp32 feats) ----------------
__global__ __launch_bounds__(256) void k_attn2(
    const float* __restrict__ proj, const float* __restrict__ hs, const float* __restrict__ hr,
    const float* __restrict__ hl, const int* __restrict__ growptr,
    float* __restrict__ q_star)
{
  __shared__ float s_q[192];
  __shared__ float s_e[512];
  __shared__ float red[256];
  const int b = blockIdx.x;
  const int beg = growptr[b], end = growptr[b+1];
  const int cnt = end - beg;
  const int t = threadIdx.x, wv = t>>6, lane = t&63;
  if (t < 192) s_q[t] = hl[(size_t)b*192 + t];
  __syncthreads();
  const float q0 = s_q[lane], q1 = s_q[64+lane], q2 = s_q[128+lane];
  const float* fbase = (t < 64) ? proj : (t < 128) ? hs : hr;
  const int fcol = lane;
  float m_run = -3.0e38f, d_run = 0.f, racc = 0.f;
  for (int c0 = 0; c0 < cnt; c0 += 512){
    int cc = min(512, cnt - c0);
    for (int i = wv; i < cc; i += 4){
      size_t o = (size_t)(beg + c0 + i)*HH;
      float v = proj[o+lane]*q0 + hs[o+lane]*q1 + hr[o+lane]*q2;
      #pragma unroll
      for (int off = 32; off > 0; off >>= 1) v += __shfl_down(v, off);
      if (lane == 0) s_e[i] = v;
    }
    __syncthreads();
    float mx = -3.0e38f;
    for (int i = t; i < cc; i += 256) mx = fmaxf(mx, s_e[i]);
    red[t] = mx; __syncthreads();
    for (int s = 128; s > 0; s >>= 1){ if (t < s) red[t] = fmaxf(red[t], red[t+s]); __syncthreads(); }
    float nm = fmaxf(m_run, red[0]);
    __syncthreads();
    float ps = 0.f;
    for (int i = t; i < cc; i += 256){ float ex = expf(s_e[i] - nm); s_e[i] = ex; ps += ex; }
    red[t] = ps; __syncthreads();
    for (int s = 128; s > 0; s >>= 1){ if (t < s) red[t] += red[t+s]; __syncthreads(); }
    float scale = (m_run > -1.0e38f) ? expf(m_run - nm) : 0.f;
    d_run = d_run*scale + red[0];
    racc *= scale;
    if (t < 192){
      for (int i = 0; i < cc; ++i)
        racc += s_e[i] * fbase[(size_t)(beg + c0 + i)*HH + fcol];
    }
    m_run = nm;
    __syncthreads();
  }
  if (t < 192){
    q_star[(size_t)b*384 + t] = s_q[t];
    q_star[(size_t)b*384 + 192 + t] = (cnt > 0) ? racc/d_run : 0.f;
  }
}

// ---------------- final: out = PReLU(q_star@W_sp^T + b_sp), fp32 weights ----------------
__global__ __launch_bounds__(256) void k_final(
    const float* __restrict__ q_star, const float* __restrict__ W, const float* __restrict__ bias,
    const float* __restrict__ prelu_a, float* __restrict__ out)
{
  __shared__ float s_q[8][384];
  const int t = threadIdx.x;
  const int b0 = blockIdx.x * 8;
  for (int i = t; i < 8*384; i += 256){ int g=i/384, k=i%384; s_q[g][k] = q_star[(size_t)(b0+g)*384 + k]; }
  __syncthreads();
  float a = prelu_a[0];
  float acc[4][8];
  #pragma unroll
  for (int m = 0; m < 4; ++m){
    float bb = bias[t + 256*m];
    #pragma unroll
    for (int g = 0; g < 8; ++g) acc[m][g] = bb;
  }
  for (int k4 = 0; k4 < 96; ++k4){
    float4 w0 = *(const float4*)&W[(size_t)(t)*384     + k4*4];
    float4 w1 = *(const float4*)&W[(size_t)(t+256)*384 + k4*4];
    float4 w2 = *(const float4*)&W[(size_t)(t+512)*384 + k4*4];
    float4 w3 = *(const float4*)&W[(size_t)(t+768)*384 + k4*4];
    #pragma unroll
    for (int g = 0; g < 8; ++g){
      float4 q = *(const float4*)&s_q[g][k4*4];
      acc[0][g] += dot4_(w0,q); acc[1][g] += dot4_(w1,q);
      acc[2][g] += dot4_(w2,q); acc[3][g] += dot4_(w3,q);
    }
  }
  #pragma unroll
  for (int m = 0; m < 4; ++m){
    int j = t + 256*m;
    #pragma unroll
    for (int g = 0; g < 8; ++g){
      float z = acc[m][g];
      out[(size_t)(b0+g)*RO + j] = (z >= 0.f) ? z : a*z;
    }
  }
}

extern "C" void kernel_launch(void* const* d_in, const int* in_sizes, int n_in,
                              void* d_out, int out_size, void* d_ws, size_t ws_size,
                              hipStream_t stream) {
  const float* x       = (const float*)d_in[0];
  const int*   ei      = (const int*)d_in[1];
  const int*   batch   = (const int*)d_in[3];
  const float* W_p     = (const float*)d_in[4];
  const float* b_p     = (const float*)d_in[5];
  const float* W_l     = (const float*)d_in[6];
  const float* b_l     = (const float*)d_in[7];
  const float* W_r     = (const float*)d_in[8];
  const float* gs_W    = (const float*)d_in[9];
  const float* gs_b    = (const float*)d_in[10];
  const float* gr_W    = (const float*)d_in[11];
  const float* gr_b    = (const float*)d_in[12];
  const float* grus_Wih= (const float*)d_in[13];
  const float* grus_Whh= (const float*)d_in[14];
  const float* grus_bih= (const float*)d_in[15];
  const float* grus_bhh= (const float*)d_in[16];
  const float* grur_Wih= (const float*)d_in[17];
  const float* grur_Whh= (const float*)d_in[18];
  const float* grur_bih= (const float*)d_in[19];
  const float* grur_bhh= (const float*)d_in[20];
  const float* lstm_Wih= (const float*)d_in[21];
  const float* lstm_Whh= (const float*)d_in[22];
  const float* lstm_bih= (const float*)d_in[23];
  const float* lstm_bhh= (const float*)d_in[24];
  const float* W_sp    = (const float*)d_in[25];
  const float* b_sp    = (const float*)d_in[26];
  const float* prelu_a = (const float*)d_in[27];

  float* out = (float*)d_out;
  char* w = (char*)d_ws;
  size_t off = 0;
  auto A = [&](size_t bytes){ size_t o = off; off += (bytes + 255) & ~(size_t)255; return o; };

  int*   cnt     = (int*)(w + A((size_t)NN*4));
  int*   rowptr  = (int*)(w + A((size_t)(NN+1)*4));
  int*   fill    = (int*)(w + A((size_t)NN*4));
  int*   col     = (int*)(w + A((size_t)NE*4));
  int*   gcnt    = (int*)(w + A((size_t)NB*4));
  int*   growptr = (int*)(w + A((size_t)(NB+1)*4));
  float* proj    = (float*)(w + A((size_t)NN*HH*4));
  float* hs      = (float*)(w + A((size_t)NN*HH*4));
  float* hr      = (float*)(w + A((size_t)NN*HH*4));
  float* agg     = (float*)(w + A((size_t)NN*HH*4));   // doubles as am (in-place)
  u16*   hsb     = (u16*)(w + A((size_t)NN*HH*2));
  float* qstar   = (float*)(w + A((size_t)NB*384*4));
  float* hlA     = (float*)(w + A((size_t)NB*192*4));
  float* clA     = (float*)(w + A((size_t)NB*192*4));
  float* hlB     = (float*)(w + A((size_t)NB*192*4));
  float* clB     = (float*)(w + A((size_t)NB*192*4));
  u16*   pB_proj = (u16*)(w + A((size_t)8192*2));
  u16*   pB_sage = (u16*)(w + A((size_t)8192*2));
  u16*   pB_gruS = (u16*)(w + A((size_t)24576*2));
  u16*   pB_gruR = (u16*)(w + A((size_t)24576*2));

  const int* src = ei;
  const int* dst = ei + NE;

  hipMemsetAsync(cnt,   0, (size_t)NN*4, stream);
  hipMemsetAsync(gcnt,  0, (size_t)NB*4, stream);
  hipMemsetAsync(qstar, 0, (size_t)NB*384*4, stream);
  hipMemsetAsync(hlA,   0, (size_t)NB*192*4, stream);
  hipMemsetAsync(clA,   0, (size_t)NB*192*4, stream);

  k_cnt  <<<1024, 256, 0, stream>>>(dst, batch, cnt, gcnt);
  k_scan2<<<2, 1024, 0, stream>>>(cnt, rowptr, fill, NN, gcnt, growptr, NB);
  k_fill <<<1024, 256, 0, stream>>>(src, dst, fill, col);
  k_prep <<<32, 256, 0, stream>>>(W_p, W_l, W_r, grus_Wih, grus_Whh, grur_Wih, grur_Whh,
                                  pB_proj, pB_sage, pB_gruS, pB_gruR);

  const int NT = (NN + 63)/64;   // 1563 node tiles
  k_proj<<<NT, 256, 0, stream>>>(x, pB_proj, b_p, proj, hs, hr, hsb);

  float* gates_out = out + (size_t)NB*RO;
  for (int s = 0; s < 3; ++s){
    k_agg <<<NN/4, 256, 0, stream>>>(hsb, rowptr, col, agg);
    k_sage<<<NT, 256, 0, stream>>>(hsb, pB_sage, b_l, agg);
    k_gru <<<NT, 256, 0, stream>>>(hs, agg, gs_W, gs_b, pB_gruS,
                                   grus_bih, grus_bhh, (float*)nullptr, hsb);
    k_gru <<<NT, 256, 0, stream>>>(hr, agg, gr_W, gr_b, pB_gruR,
                                   grur_bih, grur_bhh, gates_out + (size_t)s*NN, (u16*)nullptr);
  }

  float* hin = hlA; float* cin = clA; float* hout = hlB; float* cout_ = clB;
  for (int t = 0; t < 3; ++t){
    k_lstm<<<NB/8, 256, 0, stream>>>(qstar, hin, cin, lstm_Wih, lstm_Whh, lstm_bih, lstm_bhh, hout, cout_);
    k_attn2<<<NB, 256, 0, stream>>>(proj, hs, hr, hout, growptr, qstar);
    float* th = hin; hin = hout; hout = th;
    float* tc = cin; cin = cout_; cout_ = tc;
  }

  k_final<<<NB/8, 256, 0, stream>>>(qstar, W_sp, b_sp, prelu_a, out);
}

// Round 7
// 1728.646 us; speedup vs baseline: 1.0782x; 1.0782x over previous
//
#include <hip/hip_runtime.h>
#include <math.h>

#define NN 100000      // nodes
#define NE 3200000     // edges
#define NIN 128
#define HH 64
#define NB 2048        // graphs
#define RO 1024

typedef unsigned short u16;
typedef __attribute__((ext_vector_type(8))) short short8;
typedef __attribute__((ext_vector_type(4))) float f32x4;

__device__ __forceinline__ float sigmoidf_(float x){ return 1.f/(1.f+expf(-x)); }
__device__ __forceinline__ float dot4_(float4 a, float4 b){ return a.x*b.x + a.y*b.y + a.z*b.z + a.w*b.w; }
__device__ __forceinline__ u16 f2bf(float f){
  unsigned u = __float_as_uint(f);
  return (u16)((u + 0x7FFFu + ((u>>16)&1u)) >> 16);
}
__device__ __forceinline__ float bf2f(u16 v){
  return __uint_as_float(((unsigned)v) << 16);
}

// ---------------- CSR build ----------------
__global__ void k_cnt(const int* __restrict__ dst, const int* __restrict__ batch,
                      int* __restrict__ cnt, int* __restrict__ gcnt){
  int g = blockIdx.x*256 + threadIdx.x;
  if (g < NE) atomicAdd(&cnt[dst[g]], 1);
  int n = g - NE;
  if (n >= 0 && n < NN) atomicAdd(&gcnt[batch[n]], 1);
}
// two single-block exclusive scans (block 0: nodes, block 1: graphs)
// also seeds fill2[i] = exclusive prefix (so k_fill needs no rowptr read)
__device__ void scan_body(const int* in, int* out, int* fill2, int n){
  __shared__ int sums[1024];
  int tid = threadIdx.x;
  int chunk = (n + 1023) >> 10;
  int beg = tid * chunk; if (beg > n) beg = n;
  int end = beg + chunk; if (end > n) end = n;
  int s = 0;
  for (int i = beg; i < end; ++i) s += in[i];
  sums[tid] = s; __syncthreads();
  for (int off = 1; off < 1024; off <<= 1){
    int v = (tid >= off) ? sums[tid-off] : 0;
    __syncthreads();
    sums[tid] += v;
    __syncthreads();
  }
  int base = (tid==0) ? 0 : sums[tid-1];
  for (int i = beg; i < end; ++i){
    out[i] = base;
    if (fill2 != nullptr) fill2[i] = base;
    base += in[i];
  }
  if (tid == 1023) out[n] = base;
}
__global__ void k_scan2(const int* __restrict__ in0, int* __restrict__ out0, int* __restrict__ fill0, int n0,
                        const int* __restrict__ in1, int* __restrict__ out1, int n1){
  if (blockIdx.x == 0) scan_body(in0, out0, fill0, n0);
  else scan_body(in1, out1, nullptr, n1);
}
// fill[] pre-seeded with rowptr: atomicAdd gives the absolute col slot directly
__global__ void k_fill(const int* __restrict__ src, const int* __restrict__ dst,
                       int* __restrict__ fill, int* __restrict__ col){
  int e = blockIdx.x*256 + threadIdx.x;
  if (e < NE){
    int p = atomicAdd(&fill[dst[e]], 1);
    col[p] = src[e];
  }
}

// ---------------- weight prep: bf16 + fragment pre-swizzle (MFMA kernels only) ----------------
__global__ void k_prep(
    const float* __restrict__ Wp, const float* __restrict__ Wl, const float* __restrict__ Wr,
    const float* __restrict__ sWih, const float* __restrict__ sWhh,
    const float* __restrict__ rWih, const float* __restrict__ rWhh,
    u16* __restrict__ pB_proj, u16* __restrict__ pB_sage,
    u16* __restrict__ pB_gruS, u16* __restrict__ pB_gruR)
{
  int id = blockIdx.x*256 + threadIdx.x;
  if (id >= 8192) return;
  const float* sp; u16* d;
  if (id < 1024){
    int fi = id; d = pB_proj + (size_t)fi*8;
    int lane = fi&63, kt=(fi>>6)&3, ct=fi>>8;
    int rr = ct*16 + (lane&15), k0 = kt*32 + (lane>>4)*8;
    sp = &Wp[(size_t)rr*NIN + k0];
  } else if (id < 2048){
    int fi = id - 1024; d = pB_sage + (size_t)fi*8;
    int lane = fi&63, kt=(fi>>6)&3, ct=fi>>8;
    int rr = ct*16 + (lane&15), k0 = kt*32 + (lane>>4)*8;
    sp = (k0 < 64) ? &Wl[(size_t)rr*HH + k0] : &Wr[(size_t)rr*HH + (k0-64)];
  } else {
    int base = id - 2048;
    const float* Wih; const float* Whh; u16* pb; int fi;
    if (base < 3072){ pb = pB_gruS; Wih = sWih; Whh = sWhh; fi = base; }
    else            { pb = pB_gruR; Wih = rWih; Whh = rWhh; fi = base - 3072; }
    int lane = fi&63, kt=(fi>>6)&1, c2=fi>>7;
    const float* W2 = (c2 < 12) ? Wih : Whh;
    int ct = (c2 < 12) ? c2 : c2 - 12;
    int rr = ct*16 + (lane&15), k0 = kt*32 + (lane>>4)*8;
    sp = &W2[(size_t)rr*HH + k0];
    d = pb + (size_t)fi*8;
  }
  #pragma unroll
  for (int q = 0; q < 8; ++q) d[q] = f2bf(sp[q]);
}

// ---------------- proj = relu(x@W_p^T + b) via MFMA; init proj, hs, hr, hsb ----------------
__global__ __launch_bounds__(256) void k_proj(
    const float* __restrict__ x, const u16* __restrict__ pB, const float* __restrict__ bp,
    float* __restrict__ proj, float* __restrict__ hs, float* __restrict__ hr,
    u16* __restrict__ hsb)
{
  __shared__ u16 s_a[64][136];
  __shared__ u16 s_b[4*4*64*8];
  __shared__ float s_bias[64];
  const int t = threadIdx.x;
  const int n0 = blockIdx.x * 64;
  for (int idx = t; idx < 1024; idx += 256)
    ((short8*)s_b)[idx] = ((const short8*)pB)[idx];
  if (t < 64) s_bias[t] = bp[t];
  {
    int r = t>>2, cg = t&3, node = n0 + r;
    u16* d = &s_a[r][cg*32];
    if (node < NN){
      const float4* xp = (const float4*)&x[(size_t)node*NIN + cg*32];
      #pragma unroll
      for (int q = 0; q < 8; ++q){
        float4 v = xp[q];
        d[q*4+0]=f2bf(v.x); d[q*4+1]=f2bf(v.y); d[q*4+2]=f2bf(v.z); d[q*4+3]=f2bf(v.w);
      }
    } else {
      #pragma unroll
      for (int q = 0; q < 32; ++q) d[q] = 0;
    }
  }
  __syncthreads();
  const int lane = t & 63, nt = t >> 6;
  const int colp = lane & 15, rowg = lane >> 4;
  f32x4 acc[4];
  #pragma unroll
  for (int i = 0; i < 4; ++i) acc[i] = (f32x4){0.f,0.f,0.f,0.f};
  #pragma unroll
  for (int kt = 0; kt < 4; ++kt){
    short8 a = *(const short8*)&s_a[nt*16 + colp][kt*32 + rowg*8];
    #pragma unroll
    for (int ct = 0; ct < 4; ++ct){
      short8 b = *(const short8*)&s_b[((ct*4 + kt)*64 + lane)*8];
      acc[ct] = __builtin_amdgcn_mfma_f32_16x16x32_bf16(a, b, acc[ct], 0, 0, 0);
    }
  }
  #pragma unroll
  for (int reg = 0; reg < 4; ++reg){
    int node = n0 + nt*16 + rowg*4 + reg;
    if (node >= NN) continue;
    #pragma unroll
    for (int ct = 0; ct < 4; ++ct){
      int j = ct*16 + colp;
      float v = fmaxf(acc[ct][reg] + s_bias[j], 0.f);
      size_t o = (size_t)node*HH + j;
      proj[o] = v; hs[o] = v; hr[o] = v;
      hsb[o] = f2bf(v);
    }
  }
}

// ---------------- agg[n] = mean over neighbors of hsb; 8-neighbor ILP ----------------
// lane = (slot=lane>>3, colgrp=lane&7). Each lane loads 16B (8 bf16) of neighbor
// beg+slot+8k -> wave covers 8 neighbors per round. shfl_xor 8/16/32 combines slots.
__global__ __launch_bounds__(256) void k_agg(
    const u16* __restrict__ hb, const int* __restrict__ rowptr,
    const int* __restrict__ col, float* __restrict__ agg)
{
  int node = blockIdx.x*4 + (threadIdx.x >> 6);
  int lane = threadIdx.x & 63;
  if (node >= NN) return;
  int beg = rowptr[node], end = rowptr[node+1];
  const int slot = lane >> 3;
  const int c8 = (lane & 7) * 8;
  float a0=0.f,a1=0.f,a2=0.f,a3=0.f,a4=0.f,a5=0.f,a6=0.f,a7=0.f;
  for (int i = beg + slot; i < end; i += 8){
    int nb = col[i];
    short8 v = *(const short8*)&hb[(size_t)nb*HH + c8];
    a0 += bf2f((u16)v[0]); a1 += bf2f((u16)v[1]);
    a2 += bf2f((u16)v[2]); a3 += bf2f((u16)v[3]);
    a4 += bf2f((u16)v[4]); a5 += bf2f((u16)v[5]);
    a6 += bf2f((u16)v[6]); a7 += bf2f((u16)v[7]);
  }
  #pragma unroll
  for (int m = 8; m <= 32; m <<= 1){
    a0 += __shfl_xor(a0, m); a1 += __shfl_xor(a1, m);
    a2 += __shfl_xor(a2, m); a3 += __shfl_xor(a3, m);
    a4 += __shfl_xor(a4, m); a5 += __shfl_xor(a5, m);
    a6 += __shfl_xor(a6, m); a7 += __shfl_xor(a7, m);
  }
  if (slot == 0){
    float invd = 1.f / fmaxf((float)(end - beg), 1.f);
    float4 w0 = {a0*invd, a1*invd, a2*invd, a3*invd};
    float4 w1 = {a4*invd, a5*invd, a6*invd, a7*invd};
    float4* d4 = (float4*)&agg[(size_t)node*HH + c8];
    d4[0] = w0; d4[1] = w1;
  }
}

// ---------------- am = relu([agg|hs]@[Wl;Wr]^T + bl) via MFMA, fp32 in-place ----------------
__global__ __launch_bounds__(256) void k_sage(
    const u16* __restrict__ hsb, const u16* __restrict__ pB,
    const float* __restrict__ bl, float* __restrict__ agg)
{
  __shared__ u16 s_a[64][136];
  __shared__ u16 s_b[4*4*64*8];
  __shared__ float s_bias[64];
  const int t = threadIdx.x;
  const int n0 = blockIdx.x * 64;
  for (int idx = t; idx < 1024; idx += 256)
    ((short8*)s_b)[idx] = ((const short8*)pB)[idx];
  if (t < 64) s_bias[t] = bl[t];
  {
    int r = t>>2, cg = t&3, node = n0 + r;
    if (node < NN){
      if (cg < 2){
        u16* d = &s_a[r][cg*32];
        const float4* xp = (const float4*)&agg[(size_t)node*HH + cg*32];
        #pragma unroll
        for (int q = 0; q < 8; ++q){
          float4 v = xp[q];
          d[q*4+0]=f2bf(v.x); d[q*4+1]=f2bf(v.y); d[q*4+2]=f2bf(v.z); d[q*4+3]=f2bf(v.w);
        }
      } else {
        short8* d8 = (short8*)&s_a[r][cg*32];
        const short8* sp = (const short8*)&hsb[(size_t)node*HH + (cg-2)*32];
        d8[0] = sp[0]; d8[1] = sp[1]; d8[2] = sp[2]; d8[3] = sp[3];
      }
    } else {
      u16* dz = &s_a[r][cg*32];
      #pragma unroll
      for (int q = 0; q < 32; ++q) dz[q] = 0;
    }
  }
  __syncthreads();
  const int lane = t & 63, nt = t >> 6;
  const int colp = lane & 15, rowg = lane >> 4;
  f32x4 acc[4];
  #pragma unroll
  for (int i = 0; i < 4; ++i) acc[i] = (f32x4){0.f,0.f,0.f,0.f};
  #pragma unroll
  for (int kt = 0; kt < 4; ++kt){
    short8 a = *(const short8*)&s_a[nt*16 + colp][kt*32 + rowg*8];
    #pragma unroll
    for (int ct = 0; ct < 4; ++ct){
      short8 b = *(const short8*)&s_b[((ct*4 + kt)*64 + lane)*8];
      acc[ct] = __builtin_amdgcn_mfma_f32_16x16x32_bf16(a, b, acc[ct], 0, 0, 0);
    }
  }
  __syncthreads();   // all reads of agg done before in-place write
  #pragma unroll
  for (int reg = 0; reg < 4; ++reg){
    int node = n0 + nt*16 + rowg*4 + reg;
    if (node >= NN) continue;
    #pragma unroll
    for (int ct = 0; ct < 4; ++ct){
      int j = ct*16 + colp;
      float v = fmaxf(acc[ct][reg] + s_bias[j], 0.f);
      agg[(size_t)node*HH + j] = v;
    }
  }
}

// ---------------- fused gate + GRU cell via MFMA, in-place h update ----------------
__global__ __launch_bounds__(256) void k_gru(
    float* __restrict__ h, const float* __restrict__ am,
    const float* __restrict__ gW, const float* __restrict__ gb,
    const u16* __restrict__ pB,
    const float* __restrict__ bih, const float* __restrict__ bhh,
    float* __restrict__ out_gate, u16* __restrict__ bfout)
{
  __shared__ u16 s_b[2*12*2*64*8];      // 49152 B
  __shared__ u16 s_x[64][72];
  __shared__ u16 s_h[64][72];
  __shared__ float s_bi[192], s_bh[192];
  const int t = threadIdx.x;
  const int n0 = blockIdx.x * 64;
  for (int idx = t; idx < 3072; idx += 256)
    ((short8*)s_b)[idx] = ((const short8*)pB)[idx];
  if (t < 192){ s_bi[t] = bih[t]; s_bh[t] = bhh[t]; }
  const float gb0 = gb[0];
  {
    int r = t>>2, cg = t&3, node = n0 + r;
    u16* dh = &s_h[r][cg*16];
    u16* dx = &s_x[r][cg*16];
    if (node < NN){
      float hv[16];
      const float4* hp = (const float4*)&h[(size_t)node*HH + cg*16];
      #pragma unroll
      for (int q = 0; q < 4; ++q){
        float4 v = hp[q];
        hv[q*4+0]=v.x; hv[q*4+1]=v.y; hv[q*4+2]=v.z; hv[q*4+3]=v.w;
      }
      const float* gwp = &gW[cg*16];
      float p = 0.f;
      #pragma unroll
      for (int q = 0; q < 16; ++q) p += hv[q]*gwp[q];
      p += __shfl_xor(p, 1);
      p += __shfl_xor(p, 2);
      float gate = sigmoidf_(p + gb0);
      if (out_gate != nullptr && cg == 0) out_gate[node] = gate;
      #pragma unroll
      for (int q = 0; q < 16; ++q) dh[q] = f2bf(hv[q]);
      const float4* ap = (const float4*)&am[(size_t)node*HH + cg*16];
      #pragma unroll
      for (int q = 0; q < 4; ++q){
        float4 v = ap[q];
        dx[q*4+0]=f2bf(gate*v.x); dx[q*4+1]=f2bf(gate*v.y);
        dx[q*4+2]=f2bf(gate*v.z); dx[q*4+3]=f2bf(gate*v.w);
      }
    } else {
      #pragma unroll
      for (int q = 0; q < 16; ++q){ dh[q] = 0; dx[q] = 0; }
    }
  }
  __syncthreads();
  const int lane = t & 63, nt = t >> 6;
  const int colp = lane & 15, rowg = lane >> 4;
  f32x4 acc[24];
  #pragma unroll
  for (int i = 0; i < 24; ++i) acc[i] = (f32x4){0.f,0.f,0.f,0.f};
  const int arow = nt*16 + colp;
  #pragma unroll
  for (int kt = 0; kt < 2; ++kt){
    short8 ax = *(const short8*)&s_x[arow][kt*32 + rowg*8];
    short8 ah = *(const short8*)&s_h[arow][kt*32 + rowg*8];
    #pragma unroll
    for (int ct = 0; ct < 12; ++ct){
      short8 b0 = *(const short8*)&s_b[((ct*2 + kt)*64 + lane)*8];
      acc[ct] = __builtin_amdgcn_mfma_f32_16x16x32_bf16(ax, b0, acc[ct], 0, 0, 0);
      short8 b1 = *(const short8*)&s_b[(((12 + ct)*2 + kt)*64 + lane)*8];
      acc[12+ct] = __builtin_amdgcn_mfma_f32_16x16x32_bf16(ah, b1, acc[12+ct], 0, 0, 0);
    }
  }
  #pragma unroll
  for (int reg = 0; reg < 4; ++reg){
    int node = n0 + nt*16 + rowg*4 + reg;
    if (node >= NN) continue;
    #pragma unroll
    for (int jt = 0; jt < 4; ++jt){
      int j = jt*16 + colp;
      float ir = acc[jt][reg]      + s_bi[j];
      float iz = acc[4+jt][reg]    + s_bi[64+j];
      float in_ = acc[8+jt][reg]   + s_bi[128+j];
      float hr_ = acc[12+jt][reg]  + s_bh[j];
      float hz = acc[16+jt][reg]   + s_bh[64+j];
      float hn = acc[20+jt][reg]   + s_bh[128+j];
      float rg = sigmoidf_(ir + hr_);
      float zg = sigmoidf_(iz + hz);
      float ng = tanhf(in_ + rg*hn);
      size_t o = (size_t)node*HH + j;
      float ho = h[o];
      float hv = (1.f - zg)*ng + zg*ho;
      h[o] = hv;
      if (bfout != nullptr) bfout[o] = f2bf(hv);
    }
  }
}

// ---------------- LSTM cell, 8 graphs per block (fp32 weights) ----------------
__global__ __launch_bounds__(256) void k_lstm(
    const float* __restrict__ q_star, const float* __restrict__ hin, const float* __restrict__ cin,
    const float* __restrict__ Wih, const float* __restrict__ Whh,
    const float* __restrict__ bih, const float* __restrict__ bhh,
    float* __restrict__ hout, float* __restrict__ cout)
{
  __shared__ float s_q[8][384];
  __shared__ float s_h[8][192];
  __shared__ float s_g[8][768];
  const int t = threadIdx.x;
  const int b0 = blockIdx.x * 8;
  for (int i = t; i < 8*384; i += 256){ int g=i/384, k=i%384; s_q[g][k] = q_star[(size_t)(b0+g)*384 + k]; }
  for (int i = t; i < 8*192; i += 256){ int g=i/192, k=i%192; s_h[g][k] = hin[(size_t)(b0+g)*192 + k]; }
  __syncthreads();
  float acc[3][8];
  #pragma unroll
  for (int m = 0; m < 3; ++m){
    float bb = bih[t+256*m] + bhh[t+256*m];
    #pragma unroll
    for (int g = 0; g < 8; ++g) acc[m][g] = bb;
  }
  for (int k4 = 0; k4 < 96; ++k4){
    float4 w0 = *(const float4*)&Wih[(size_t)(t)*384     + k4*4];
    float4 w1 = *(const float4*)&Wih[(size_t)(t+256)*384 + k4*4];
    float4 w2 = *(const float4*)&Wih[(size_t)(t+512)*384 + k4*4];
    #pragma unroll
    for (int g = 0; g < 8; ++g){
      float4 q = *(const float4*)&s_q[g][k4*4];
      acc[0][g] += dot4_(w0,q); acc[1][g] += dot4_(w1,q); acc[2][g] += dot4_(w2,q);
    }
  }
  for (int k4 = 0; k4 < 48; ++k4){
    float4 w0 = *(const float4*)&Whh[(size_t)(t)*192     + k4*4];
    float4 w1 = *(const float4*)&Whh[(size_t)(t+256)*192 + k4*4];
    float4 w2 = *(const float4*)&Whh[(size_t)(t+512)*192 + k4*4];
    #pragma unroll
    for (int g = 0; g < 8; ++g){
      float4 hq = *(const float4*)&s_h[g][k4*4];
      acc[0][g] += dot4_(w0,hq); acc[1][g] += dot4_(w1,hq); acc[2][g] += dot4_(w2,hq);
    }
  }
  #pragma unroll
  for (int m = 0; m < 3; ++m){
    int j = t + 256*m;
    #pragma unroll
    for (int g = 0; g < 8; ++g) s_g[g][j] = acc[m][g];
  }
  __syncthreads();
  for (int task = t; task < 8*192; task += 256){
    int g = task / 192, d = task % 192;
    float i_ = s_g[g][d], f_ = s_g[g][192+d], gg = s_g[g][384+d], o_ = s_g[g][576+d];
    float c = sigmoidf_(f_)*cin[(size_t)(b0+g)*192 + d] + sigmoidf_(i_)*tanhf(gg);
    float hn = sigmoidf_(o_)*tanhf(c);
    cout[(size_t)(b0+g)*192 + d] = c;
    hout[(size_t)(b0+g)*192 + d] = hn;
  }
}

// ---------------- fused e-dot + segment softmax + weighted sum (fp32 feats) ----------------
__global__ __launch_bounds__(256) void k_attn2(
    const float* __restrict__ proj, const float* __restrict__ hs, const float* __restrict__ hr,
    const float* __restrict__ hl, const int* __restrict__ growptr,
    float* __restrict__ q_star)
{
  __shared__ float s_q[192];
  __shared__ float s_e[512];
  __shared__ float red[256];
  const int b = blockIdx.x;
  const int beg = growptr[b], end = growptr[b+1];
  const int cnt = end - beg;
  const int t = threadIdx.x, wv = t>>6, lane = t&63;
  if (t < 192) s_q[t] = hl[(size_t)b*192 + t];
  __syncthreads();
  const float q0 = s_q[lane], q1 = s_q[64+lane], q2 = s_q[128+lane];
  const float* fbase = (t < 64) ? proj : (t < 128) ? hs : hr;
  const int fcol = lane;
  float m_run = -3.0e38f, d_run = 0.f, racc = 0.f;
  for (int c0 = 0; c0 < cnt; c0 += 512){
    int cc = min(512, cnt - c0);
    for (int i = wv; i < cc; i += 4){
      size_t o = (size_t)(beg + c0 + i)*HH;
      float v = proj[o+lane]*q0 + hs[o+lane]*q1 + hr[o+lane]*q2;
      #pragma unroll
      for (int off = 32; off > 0; off >>= 1) v += __shfl_down(v, off);
      if (lane == 0) s_e[i] = v;
    }
    __syncthreads();
    float mx = -3.0e38f;
    for (int i = t; i < cc; i += 256) mx = fmaxf(mx, s_e[i]);
    red[t] = mx; __syncthreads();
    for (int s = 128; s > 0; s >>= 1){ if (t < s) red[t] = fmaxf(red[t], red[t+s]); __syncthreads(); }
    float nm = fmaxf(m_run, red[0]);
    __syncthreads();
    float ps = 0.f;
    for (int i = t; i < cc; i += 256){ float ex = expf(s_e[i] - nm); s_e[i] = ex; ps += ex; }
    red[t] = ps; __syncthreads();
    for (int s = 128; s > 0; s >>= 1){ if (t < s) red[t] += red[t+s]; __syncthreads(); }
    float scale = (m_run > -1.0e38f) ? expf(m_run - nm) : 0.f;
    d_run = d_run*scale + red[0];
    racc *= scale;
    if (t < 192){
      for (int i = 0; i < cc; ++i)
        racc += s_e[i] * fbase[(size_t)(beg + c0 + i)*HH + fcol];
    }
    m_run = nm;
    __syncthreads();
  }
  if (t < 192){
    q_star[(size_t)b*384 + t] = s_q[t];
    q_star[(size_t)b*384 + 192 + t] = (cnt > 0) ? racc/d_run : 0.f;
  }
}

// ---------------- final: out = PReLU(q_star@W_sp^T + b_sp), fp32 weights ----------------
__global__ __launch_bounds__(256) void k_final(
    const float* __restrict__ q_star, const float* __restrict__ W, const float* __restrict__ bias,
    const float* __restrict__ prelu_a, float* __restrict__ out)
{
  __shared__ float s_q[8][384];
  const int t = threadIdx.x;
  const int b0 = blockIdx.x * 8;
  for (int i = t; i < 8*384; i += 256){ int g=i/384, k=i%384; s_q[g][k] = q_star[(size_t)(b0+g)*384 + k]; }
  __syncthreads();
  float a = prelu_a[0];
  float acc[4][8];
  #pragma unroll
  for (int m = 0; m < 4; ++m){
    float bb = bias[t + 256*m];
    #pragma unroll
    for (int g = 0; g < 8; ++g) acc[m][g] = bb;
  }
  for (int k4 = 0; k4 < 96; ++k4){
    float4 w0 = *(const float4*)&W[(size_t)(t)*384     + k4*4];
    float4 w1 = *(const float4*)&W[(size_t)(t+256)*384 + k4*4];
    float4 w2 = *(const float4*)&W[(size_t)(t+512)*384 + k4*4];
    float4 w3 = *(const float4*)&W[(size_t)(t+768)*384 + k4*4];
    #pragma unroll
    for (int g = 0; g < 8; ++g){
      float4 q = *(const float4*)&s_q[g][k4*4];
      acc[0][g] += dot4_(w0,q); acc[1][g] += dot4_(w1,q);
      acc[2][g] += dot4_(w2,q); acc[3][g] += dot4_(w3,q);
    }
  }
  #pragma unroll
  for (int m = 0; m < 4; ++m){
    int j = t + 256*m;
    #pragma unroll
    for (int g = 0; g < 8; ++g){
      float z = acc[m][g];
      out[(size_t)(b0+g)*RO + j] = (z >= 0.f) ? z : a*z;
    }
  }
}

extern "C" void kernel_launch(void* const* d_in, const int* in_sizes, int n_in,
                              void* d_out, int out_size, void* d_ws, size_t ws_size,
                              hipStream_t stream) {
  const float* x       = (const float*)d_in[0];
  const int*   ei      = (const int*)d_in[1];
  const int*   batch   = (const int*)d_in[3];
  const float* W_p     = (const float*)d_in[4];
  const float* b_p     = (const float*)d_in[5];
  const float* W_l     = (const float*)d_in[6];
  const float* b_l     = (const float*)d_in[7];
  const float* W_r     = (const float*)d_in[8];
  const float* gs_W    = (const float*)d_in[9];
  const float* gs_b    = (const float*)d_in[10];
  const float* gr_W    = (const float*)d_in[11];
  const float* gr_b    = (const float*)d_in[12];
  const float* grus_Wih= (const float*)d_in[13];
  const float* grus_Whh= (const float*)d_in[14];
  const float* grus_bih= (const float*)d_in[15];
  const float* grus_bhh= (const float*)d_in[16];
  const float* grur_Wih= (const float*)d_in[17];
  const float* grur_Whh= (const float*)d_in[18];
  const float* grur_bih= (const float*)d_in[19];
  const float* grur_bhh= (const float*)d_in[20];
  const float* lstm_Wih= (const float*)d_in[21];
  const float* lstm_Whh= (const float*)d_in[22];
  const float* lstm_bih= (const float*)d_in[23];
  const float* lstm_bhh= (const float*)d_in[24];
  const float* W_sp    = (const float*)d_in[25];
  const float* b_sp    = (const float*)d_in[26];
  const float* prelu_a = (const float*)d_in[27];

  float* out = (float*)d_out;
  char* w = (char*)d_ws;
  size_t off = 0;
  auto A = [&](size_t bytes){ size_t o = off; off += (bytes + 255) & ~(size_t)255; return o; };

  int*   cnt     = (int*)(w + A((size_t)NN*4));
  int*   rowptr  = (int*)(w + A((size_t)(NN+1)*4));
  int*   fill    = (int*)(w + A((size_t)NN*4));
  int*   col     = (int*)(w + A((size_t)NE*4));
  int*   gcnt    = (int*)(w + A((size_t)NB*4));
  int*   growptr = (int*)(w + A((size_t)(NB+1)*4));
  float* proj    = (float*)(w + A((size_t)NN*HH*4));
  float* hs      = (float*)(w + A((size_t)NN*HH*4));
  float* hr      = (float*)(w + A((size_t)NN*HH*4));
  float* agg     = (float*)(w + A((size_t)NN*HH*4));   // doubles as am (in-place)
  u16*   hsb     = (u16*)(w + A((size_t)NN*HH*2));
  float* qstar   = (float*)(w + A((size_t)NB*384*4));
  float* hlA     = (float*)(w + A((size_t)NB*192*4));
  float* clA     = (float*)(w + A((size_t)NB*192*4));
  float* hlB     = (float*)(w + A((size_t)NB*192*4));
  float* clB     = (float*)(w + A((size_t)NB*192*4));
  u16*   pB_proj = (u16*)(w + A((size_t)8192*2));
  u16*   pB_sage = (u16*)(w + A((size_t)8192*2));
  u16*   pB_gruS = (u16*)(w + A((size_t)24576*2));
  u16*   pB_gruR = (u16*)(w + A((size_t)24576*2));

  const int* src = ei;
  const int* dst = ei + NE;

  hipMemsetAsync(cnt,   0, (size_t)NN*4, stream);
  hipMemsetAsync(gcnt,  0, (size_t)NB*4, stream);
  hipMemsetAsync(qstar, 0, (size_t)NB*384*4, stream);
  hipMemsetAsync(hlA,   0, (size_t)NB*192*4, stream);
  hipMemsetAsync(clA,   0, (size_t)NB*192*4, stream);

  k_cnt  <<<(NE+NN+255)/256, 256, 0, stream>>>(dst, batch, cnt, gcnt);
  k_scan2<<<2, 1024, 0, stream>>>(cnt, rowptr, fill, NN, gcnt, growptr, NB);
  k_fill <<<(NE+255)/256, 256, 0, stream>>>(src, dst, fill, col);
  k_prep <<<32, 256, 0, stream>>>(W_p, W_l, W_r, grus_Wih, grus_Whh, grur_Wih, grur_Whh,
                                  pB_proj, pB_sage, pB_gruS, pB_gruR);

  const int NT = (NN + 63)/64;   // 1563 node tiles
  k_proj<<<NT, 256, 0, stream>>>(x, pB_proj, b_p, proj, hs, hr, hsb);

  float* gates_out = out + (size_t)NB*RO;
  for (int s = 0; s < 3; ++s){
    k_agg <<<NN/4, 256, 0, stream>>>(hsb, rowptr, col, agg);
    k_sage<<<NT, 256, 0, stream>>>(hsb, pB_sage, b_l, agg);
    k_gru <<<NT, 256, 0, stream>>>(hs, agg, gs_W, gs_b, pB_gruS,
                                   grus_bih, grus_bhh, (float*)nullptr, hsb);
    k_gru <<<NT, 256, 0, stream>>>(hr, agg, gr_W, gr_b, pB_gruR,
                                   grur_bih, grur_bhh, gates_out + (size_t)s*NN, (u16*)nullptr);
  }

  float* hin = hlA; float* cin = clA; float* hout = hlB; float* cout_ = clB;
  for (int t = 0; t < 3; ++t){
    k_lstm<<<NB/8, 256, 0, stream>>>(qstar, hin, cin, lstm_Wih, lstm_Whh, lstm_bih, lstm_bhh, hout, cout_);
    k_attn2<<<NB, 256, 0, stream>>>(proj, hs, hr, hout, growptr, qstar);
    float* th = hin; hin = hout; hout = th;
    float* tc = cin; cin = cout_; cout_ = tc;
  }

  k_final<<<NB/8, 256, 0, stream>>>(qstar, W_sp, b_sp, prelu_a, out);
}